// Round 9
// baseline (302.247 us; speedup 1.0000x reference)
//
#include <hip/hip_runtime.h>
#include <hip/hip_bf16.h>
#include <stdint.h>

constexpr int BB  = 64;    // batch
constexpr int SS  = 512;   // seq len
constexpr int HH  = 768;   // hidden
constexpr int NL  = 9;     // labels
constexpr int NROWS = BB * SS;          // 32768
constexpr int EMN   = SS * NL;          // 4608 emissions per batch
constexpr int NSEG  = 8;                // time segments for parallel lognorm
constexpr int NCH   = BB * NSEG * NL;   // 4608 lognorm basis chains
constexpr int GPW   = 7;                // chains (9-lane groups) per wave
constexpr int NLOGW = (NCH + GPW - 1) / GPW;  // 659 lognorm waves
constexpr float NEG  = -1e30f;

__device__ __forceinline__ float readlane_f(float v, int lane) {
  union { float f; int i; } u;
  u.f = v;
  u.i = __builtin_amdgcn_readlane(u.i, lane);
  return u.f;
}

// lane gather via LDS crossbar (per-lane VGPR address)
__device__ __forceinline__ float bperm_f(int byte_addr, float v) {
  union { float f; int i; } u;
  u.f = v;
  u.i = __builtin_amdgcn_ds_bpermute(byte_addr, u.i);
  return u.f;
}

// broadcast lane I (0..31, within each 32-lane half) via ds_swizzle BitMode:
// offset = (xor<<10)|(or<<5)|and, and=0, or=I, xor=0. Immediate, no addr VGPR.
#define SWZ_BCAST(dst, src, I)                                        \
  { union { float f; int i; } _u; _u.f = (src);                       \
    _u.i = __builtin_amdgcn_ds_swizzle(_u.i, ((I) << 5));             \
    (dst) = _u.f; }

__device__ __forceinline__ void swz_bcast9(float* s, float nxt) {
  SWZ_BCAST(s[0], nxt, 0); SWZ_BCAST(s[1], nxt, 1);
  SWZ_BCAST(s[2], nxt, 2); SWZ_BCAST(s[3], nxt, 3);
  SWZ_BCAST(s[4], nxt, 4); SWZ_BCAST(s[5], nxt, 5);
  SWZ_BCAST(s[6], nxt, 6); SWZ_BCAST(s[7], nxt, 7);
  SWZ_BCAST(s[8], nxt, 8);
}

// 3-input max, single instruction, depth-2 trees for 9-way max.
// EXACT: float max is associative/commutative for finite inputs (no rounding).
__device__ __forceinline__ float max3f(float a, float b, float c) {
  float d;
  asm("v_max3_f32 %0, %1, %2, %3" : "=v"(d) : "v"(a), "v"(b), "v"(c));
  return d;
}

__device__ __forceinline__ float max9f(const float* c) {
  return max3f(max3f(c[0], c[1], c[2]),
               max3f(c[3], c[4], c[5]),
               max3f(c[6], c[7], c[8]));
}

// argmax with reference tie-breaking (lowest index wins), bit-exact select tree
__device__ __forceinline__ int arg9(const float* c) {
  const bool b01 = c[0] >= c[1], b23 = c[2] >= c[3];
  const bool b45 = c[4] >= c[5], b67 = c[6] >= c[7];
  const float v01 = b01 ? c[0] : c[1]; const int i01 = b01 ? 0 : 1;
  const float v23 = b23 ? c[2] : c[3]; const int i23 = b23 ? 2 : 3;
  const float v45 = b45 ? c[4] : c[5]; const int i45 = b45 ? 4 : 5;
  const float v67 = b67 ? c[6] : c[7]; const int i67 = b67 ? 6 : 7;
  const bool bA = v01 >= v23, bB = v45 >= v67;
  const float vA = bA ? v01 : v23; const int iA = bA ? i01 : i23;
  const float vB = bB ? v45 : v67; const int iB = bB ? i45 : i67;
  const bool bC = vA >= vB;
  const float vC = bC ? vA : vB; const int iC = bC ? iA : iB;
  const bool bD = vC >= c[8];
  return bD ? iC : 8;
}

// ---------------------------------------------------------------------------
// Kernel 1: logits[b,s,l] = hidden[b,s,:] @ W[:,l] + bias[l]
// Register-blocked (W reloaded per j-slice). Blocks 0..63 compute lens[b];
// block 0 zeroes loss acc; block 1 zeroes the combine arrival counters.
// ---------------------------------------------------------------------------
__global__ __launch_bounds__(256, 4) void logits_kernel(
    const float* __restrict__ hidden, const float* __restrict__ W,
    const float* __restrict__ bias, const int* __restrict__ mask,
    float* __restrict__ logits, int* __restrict__ lens,
    float* __restrict__ out, int* __restrict__ cnt) {
  const int lane = threadIdx.x & 63;
  const int wid  = blockIdx.x * 4 + (threadIdx.x >> 6);   // 8192 waves

  if (blockIdx.x == 0 && threadIdx.x == 0) out[0] = 0.0f;
  if (blockIdx.x == 1 && threadIdx.x < BB) cnt[threadIdx.x] = 0;

  if (blockIdx.x < 64 && threadIdx.x < 64) {
    const int4* mp = (const int4*)(mask + blockIdx.x * SS);
    const int4 a = mp[threadIdx.x];
    const int4 c = mp[threadIdx.x + 64];
    int lsum = a.x + a.y + a.z + a.w + c.x + c.y + c.z + c.w;
#pragma unroll
    for (int off = 32; off >= 1; off >>= 1) lsum += __shfl_xor(lsum, off, 64);
    if (threadIdx.x == 0) lens[blockIdx.x] = lsum;
  }

  const float my_bias = (lane < NL) ? bias[lane] : 0.0f;

  const float4* hp[4];
#pragma unroll
  for (int r = 0; r < 4; ++r)
    hp[r] = (const float4*)(hidden + (size_t)(wid + r * 8192) * HH);

  float acc[4][NL];
#pragma unroll
  for (int r = 0; r < 4; ++r)
#pragma unroll
    for (int l = 0; l < NL; ++l) acc[r][l] = 0.0f;

#pragma unroll
  for (int j = 0; j < 3; ++j) {
    float w[4][NL];                      // only this j-slice of W lives
#pragma unroll
    for (int k = 0; k < 4; ++k) {
      const int r = lane * 4 + j * 256 + k;
#pragma unroll
      for (int l = 0; l < NL; ++l) w[k][l] = W[r * NL + l];
    }
#pragma unroll
    for (int r = 0; r < 4; ++r) {
      const float4 h = hp[r][lane + j * 64];
#pragma unroll
      for (int l = 0; l < NL; ++l)
        acc[r][l] += h.x * w[0][l] + h.y * w[1][l] +
                     h.z * w[2][l] + h.w * w[3][l];
    }
  }
#pragma unroll
  for (int off = 32; off >= 1; off >>= 1)
#pragma unroll
    for (int r = 0; r < 4; ++r)
#pragma unroll
      for (int l = 0; l < NL; ++l)
        acc[r][l] += __shfl_xor(acc[r][l], off, 64);
  if (lane < NL) {
#pragma unroll
    for (int r = 0; r < 4; ++r) {
      float v = acc[r][0];
#pragma unroll
      for (int l = 1; l < NL; ++l) if (lane == l) v = acc[r][l];
      logits[(size_t)(wid + r * 8192) * NL + lane] = v + my_bias;
    }
  }
}

// combine logic, run by the LAST arriving producer of each batch (73 total:
// 72 basis chains + 1 numerator). Bit-identical to the original combine.
__device__ void combine_batch(int b, int tid,
                              const float* __restrict__ logits,
                              const float* __restrict__ segmat,
                              const float* __restrict__ start_t,
                              const float* __restrict__ end_t,
                              const float* __restrict__ num_den,
                              float* __restrict__ out) {
  const int j = (tid < NL) ? tid : NL - 1;
  float s[NL];
#pragma unroll
  for (int i = 0; i < NL; ++i) s[i] = start_t[i] + logits[(size_t)b * EMN + i];
  float mcur[NL], mnxt[NL];
  {
    const float* M = segmat + (size_t)(b * NSEG) * 81;
#pragma unroll
    for (int i = 0; i < NL; ++i) mcur[i] = M[i * NL + j];
  }
  for (int sg = 0; sg < NSEG; ++sg) {
    if (sg + 1 < NSEG) {
      const float* M = segmat + (size_t)(b * NSEG + sg + 1) * 81;
#pragma unroll
      for (int i = 0; i < NL; ++i) mnxt[i] = M[i * NL + j];
    }
    float c[NL];
#pragma unroll
    for (int i = 0; i < NL; ++i) c[i] = s[i] + mcur[i];
    const float m = max9f(c);
    float sum = 0.0f;
#pragma unroll
    for (int i = 0; i < NL; ++i) sum += __expf(c[i] - m);
    const float nxt = m + __logf(sum);
#pragma unroll
    for (int i = 0; i < NL; ++i) s[i] = readlane_f(nxt, i);
#pragma unroll
    for (int i = 0; i < NL; ++i) mcur[i] = mnxt[i];
  }
  float c[NL];
#pragma unroll
  for (int i = 0; i < NL; ++i) c[i] = s[i] + end_t[i];
  const float m = max9f(c);
  float sum = 0.0f;
#pragma unroll
  for (int i = 0; i < NL; ++i) sum += __expf(c[i] - m);
  if (tid == 0) {
    const float den = m + __logf(sum);
    atomicAdd(out, (den - num_den[b]) * (1.0f / 64.0f));
  }
}

// ---------------------------------------------------------------------------
// Kernel 2: scan kernel, 755 one-wave blocks.
//   blk   0..  31 : viterbi, TWO length-rank-paired batches interleaved per
//                   wave — chain B's front+argmax issue under chain A's
//                   ~240-cyc broadcast latency (and vice versa), halving the
//                   per-step wall. Arithmetic per step identical -> bit-exact.
//   blk  32..  95 : numerator
//   blk  96.. 754 : lognorm, 7 chains per wave in 9-lane groups
//   Last arriving producer per batch runs combine in-place.
// ---------------------------------------------------------------------------
__global__ __launch_bounds__(64) void scan_kernel(
    const float* __restrict__ logits, const int* __restrict__ labels,
    const float* __restrict__ start_t, const float* __restrict__ end_t,
    const float* __restrict__ trans, float* __restrict__ out,
    float* __restrict__ num_den, const int* __restrict__ lens,
    float* __restrict__ segmat, int* __restrict__ cnt) {
  __shared__ float4   embvA[1161];              // staged emissions A, 18576 B
  __shared__ float4   embvB[1161];              // staged emissions B, 18576 B
  __shared__ uint32_t bpwA[64 * NL];            // packed backpointers A
  __shared__ uint32_t bpwB[64 * NL];            // packed backpointers B
  __shared__ unsigned char tags_s[SS];
  __shared__ unsigned char lab[SS];

  const int blk = blockIdx.x;
  const int tid = threadIdx.x;
  const int j   = (tid < NL) ? tid : NL - 1;

  if (blk < 32) {
    // ================= viterbi, 2 chains interleaved =================
    __builtin_amdgcn_s_setprio(1);
    // ---- rank batches by length; this block takes ranks 2*blk, 2*blk+1.
    // Deterministic total order (len, then index) -> a permutation; pairing
    // sorted neighbors minimizes the single-chain tail.
    const int lenv = lens[tid];
    int rank = 0;
    for (int c2 = 0; c2 < 64; ++c2) {
      const int lc = __shfl(lenv, c2, 64);
      rank += (lc < lenv || (lc == lenv && c2 < tid)) ? 1 : 0;
    }
    const unsigned long long mA = __ballot(rank == 2 * blk);
    const unsigned long long mB = __ballot(rank == 2 * blk + 1);
    const int bA = __ffsll(mA) - 1;
    const int bB = __ffsll(mB) - 1;
    const int lenA = __shfl(lenv, bA, 64);
    const int lenB = __shfl(lenv, bB, 64);
    const float* embA = logits + (size_t)bA * EMN;
    const float* embB = logits + (size_t)bB * EMN;

    // stage both batches' emissions into LDS (coalesced burst; the only
    // global reads on the viterbi path)
    {
      const float4* a4 = (const float4*)embA;
      const float4* b4 = (const float4*)embB;
#pragma unroll
      for (int i = 0; i < 18; ++i) {
        embvA[tid + i * 64] = a4[tid + i * 64];
        embvB[tid + i * 64] = b4[tid + i * 64];
      }
    }
    __syncthreads();
    const float* emb_sA = (const float*)embvA;
    const float* emb_sB = (const float*)embvB;

    float tc[NL];
#pragma unroll
    for (int i = 0; i < NL; ++i) tc[i] = trans[i * NL + j];
    float sA[NL], sB[NL];
#pragma unroll
    for (int i = 0; i < NL; ++i) {
      sA[i] = start_t[i] + emb_sA[i];
      sB[i] = start_t[i] + emb_sB[i];
    }

    float e0A[8], e1A[8], e0B[8], e1B[8];
#pragma unroll
    for (int k = 0; k < 8; ++k) {
      e0A[k] = emb_sA[(1 + k) * NL + j];
      e0B[k] = emb_sB[(1 + k) * NL + j];
    }

    const int minlen = (lenA < lenB) ? lenA : lenB;
    const int nfmin  = (minlen - 1) >> 3;   // full unguarded 8-step blocks

    // ---- phase 1: both chains active, no guards, interleaved
    for (int tb = 0; tb < nfmin; ++tb) {
      const int tbase = 8 * tb;
#pragma unroll
      for (int k = 0; k < 8; ++k) {
        e1A[k] = emb_sA[(tbase + 9 + k) * NL + j];
        e1B[k] = emb_sB[(tbase + 9 + k) * NL + j];
      }
      uint32_t wA = 0, wB = 0;
#pragma unroll
      for (int k = 0; k < 8; ++k) {
        {
          float c[NL];
#pragma unroll
          for (int i = 0; i < NL; ++i) c[i] = sA[i] + tc[i];
          const float best = max9f(c);
          const float nxt  = best + e0A[k];
          swz_bcast9(sA, nxt);                 // issue A broadcast early
          wA |= (uint32_t)arg9(c) << (4 * k);  // off-path, fills A latency
        }
        {
          float c[NL];
#pragma unroll
          for (int i = 0; i < NL; ++i) c[i] = sB[i] + tc[i];
          const float best = max9f(c);
          const float nxt  = best + e0B[k];
          swz_bcast9(sB, nxt);
          wB |= (uint32_t)arg9(c) << (4 * k);  // fills B latency (next is A)
        }
      }
      if (tid < NL) { bpwA[tb * NL + tid] = wA; bpwB[tb * NL + tid] = wB; }
#pragma unroll
      for (int k = 0; k < 8; ++k) { e0A[k] = e1A[k]; e0B[k] = e1B[k]; }
    }
    // ---- phase 2: remainder, wave-uniform guards per chain, direct e-reads
    for (int tb = nfmin; tb < 64; ++tb) {
      const int t0 = 8 * tb + 1;
      if (t0 >= lenA && t0 >= lenB) break;
      uint32_t wA = 0, wB = 0;
#pragma unroll
      for (int k = 0; k < 8; ++k) {
        const int t = t0 + k;
        if (t < lenA) {
          const float e = emb_sA[t * NL + j];
          float c[NL];
#pragma unroll
          for (int i = 0; i < NL; ++i) c[i] = sA[i] + tc[i];
          const float best = max9f(c);
          const float nxt  = best + e;
          swz_bcast9(sA, nxt);
          wA |= (uint32_t)arg9(c) << (4 * k);
        }
        if (t < lenB) {
          const float e = emb_sB[t * NL + j];
          float c[NL];
#pragma unroll
          for (int i = 0; i < NL; ++i) c[i] = sB[i] + tc[i];
          const float best = max9f(c);
          const float nxt  = best + e;
          swz_bcast9(sB, nxt);
          wB |= (uint32_t)arg9(c) << (4 * k);
        }
      }
      if (tid < NL) { bpwA[tb * NL + tid] = wA; bpwB[tb * NL + tid] = wB; }
    }
    // fix-up upper-half lanes (swizzle acts within 32-lane halves; lanes
    // 32..63 hold garbage state). Lane 0 is always correct.
#pragma unroll
    for (int i = 0; i < NL; ++i) {
      sA[i] = readlane_f(sA[i], 0);
      sB[i] = readlane_f(sB[i], 0);
    }
    __syncthreads();   // drain LDS before backtraces

    // ---- backtrace + output, chain A then chain B (identical logic)
    for (int ch = 0; ch < 2; ++ch) {
      const uint32_t* bp = (ch == 0) ? bpwA : bpwB;
      const float*    sv = (ch == 0) ? sA : sB;
      const int       ln = (ch == 0) ? lenA : lenB;
      const int       bb = (ch == 0) ? bA : bB;

      float bv = sv[0] + end_t[0];
      int   bl = 0;
#pragma unroll
      for (int i = 1; i < NL; ++i) {
        const float cc = sv[i] + end_t[i];
        if (cc > bv) { bv = cc; bl = i; }
      }
      // chunked map composition (lane tid owns t = 8*tid+1..8*tid+8)
      uint32_t wv_[NL];
#pragma unroll
      for (int x = 0; x < NL; ++x) wv_[x] = bp[tid * NL + x];
      uint64_t C = 0x876543210ULL;
#pragma unroll
      for (int k = 1; k <= 8; ++k) {
        const int t = 8 * tid + k;
        uint64_t nc = 0;
#pragma unroll
        for (int x = 0; x < 9; ++x) {
          const int g = (int)((wv_[x] >> (4 * (k - 1))) & 15u);
          nc |= ((C >> (4 * g)) & 15ULL) << (4 * x);
        }
        C = (t < ln) ? nc : C;
      }
      const uint32_t Clo = (uint32_t)C, Chi = (uint32_t)(C >> 32);
      uint32_t cur = (uint32_t)bl;
      int bnd = 0;
#pragma unroll
      for (int c = 63; c >= 0; --c) {
        bnd = (tid == c) ? (int)cur : bnd;
        const uint32_t lo = (uint32_t)__builtin_amdgcn_readlane((int)Clo, c);
        const uint32_t hi = (uint32_t)__builtin_amdgcn_readlane((int)Chi, c);
        const uint64_t cc = ((uint64_t)hi << 32) | lo;
        cur = (uint32_t)((cc >> (4 * cur)) & 15u);
      }
      int tag = bnd;
#pragma unroll
      for (int k = 8; k >= 1; --k) {
        const int t = 8 * tid + k;
        const int tt = (t < 512) ? t : 511;
        const int blk2 = (tt - 1) >> 3;
        const int kk   = tt - 8 * blk2;
        const uint32_t bw = bp[blk2 * NL + tag];
        const int nt = (int)((bw >> (4 * (kk - 1))) & 15u);
        tag = (t < ln) ? nt : tag;
        tags_s[t - 1] = (unsigned char)tag;
      }
      __syncthreads();
      for (int i = tid; i < EMN; i += 64) {
        const int t = i / NL;
        const int l = i - t * NL;
        out[1 + (size_t)bb * EMN + i] =
            (t < ln && l == (int)tags_s[t]) ? 1.0f : 0.0f;
      }
      __syncthreads();
    }

  } else if (blk < 96) {
    // ================= numerator =================
    const int b   = blk - 32;
    const int len = lens[b];
    const float* emb = logits + (size_t)b * EMN;
    for (int t = tid; t < SS; t += 64) {
      const int v = labels[b * SS + t];
      lab[t] = (unsigned char)((v == -100) ? 0 : v);
    }
    __syncthreads();
    float contrib = 0.0f;
    for (int t = tid; t < SS; t += 64) {
      if (t >= 1 && t < len)
        contrib += emb[t * NL + lab[t]] + trans[lab[t - 1] * NL + lab[t]];
    }
#pragma unroll
    for (int off = 32; off >= 1; off >>= 1)
      contrib += __shfl_xor(contrib, off, 64);
    if (tid == 0) {
      const int l0 = lab[0];
      num_den[b] = start_t[l0] + emb[l0] + contrib + end_t[lab[len - 1]];
    }
    __threadfence();
    int old = -1;
    if (tid == 0) old = atomicAdd(&cnt[b], 1);
    old = __builtin_amdgcn_readlane(old, 0);
    if (old == 72) {
      __threadfence();
      combine_batch(b, tid, logits, segmat, start_t, end_t, num_den, out);
    }

  } else {
    // ============ lognorm: 7 chains per wave, 9-lane groups ============
    const int w   = blk - 96;                // 0..658
    const int g   = tid / 9;                 // 0..7 (g==7: lane 63, idle)
    const int i   = tid - 9 * g;             // state index within group
    const int cid = GPW * w + g;
    const bool valid = (g < GPW) && (cid < NCH);
    const int cc  = valid ? cid : (NCH - 1); // idle lanes duplicate last chain
    const int pr  = cc / 9;                  // (b, sg) pair
    const int e   = cc - 9 * pr;             // basis index
    const int b   = pr >> 3;
    const int sg  = pr & 7;
    const int len = lens[b];
    const int base4 = (g < GPW) ? (9 * g * 4) : 0;   // group gather base
    const float* embp = logits + (size_t)b * EMN + i;

    float tc[NL];
#pragma unroll
    for (int k = 0; k < NL; ++k) tc[k] = trans[k * NL + i];
    float my = (i == e) ? 0.0f : NEG;        // basis initial state
    const int tbeg = 64 * sg + 1;

    float eA = embp[(size_t)(tbeg    ) * NL], eB = embp[(size_t)(tbeg + 1) * NL];
    float eC = embp[(size_t)(tbeg + 2) * NL], eD = embp[(size_t)(tbeg + 3) * NL];

    for (int st = 0; st < 64; ++st) {
      const int t = tbeg + st;               // per-lane absolute time
      if (__ballot((g < GPW) && (t < len)) == 0ull) break;
      float s[NL], c[NL];
#pragma unroll
      for (int k = 0; k < NL; ++k) s[k] = bperm_f(base4 + 4 * k, my);
#pragma unroll
      for (int k = 0; k < NL; ++k) c[k] = s[k] + tc[k];
      const float m = max9f(c);
      float u = 0.0f;
#pragma unroll
      for (int k = 0; k < NL; ++k) u += __expf(c[k] - m);
      const float nv = m + __logf(u) + eA;
      my = (t < len) ? nv : my;              // reference mask semantics
      eA = eB; eB = eC; eC = eD;
      eD = embp[(size_t)(t + 4) * NL];
    }
    if (valid) segmat[(size_t)pr * 81 + e * NL + i] = my;
    __threadfence();
    int old = -1;
    if (valid && i == 0) old = atomicAdd(&cnt[b], 1);
#pragma unroll
    for (int g2 = 0; g2 < GPW; ++g2) {
      const int og = __builtin_amdgcn_readlane(old, 9 * g2);
      if (og == 72) {
        const int bg = __builtin_amdgcn_readlane(b, 9 * g2);
        __threadfence();
        combine_batch(bg, tid, logits, segmat, start_t, end_t, num_den, out);
      }
    }
  }
}

extern "C" void kernel_launch(void* const* d_in, const int* in_sizes, int n_in,
                              void* d_out, int out_size, void* d_ws, size_t ws_size,
                              hipStream_t stream) {
  const float* hidden  = (const float*)d_in[0];
  const int*   mask    = (const int*)d_in[1];
  const int*   labels  = (const int*)d_in[2];
  const float* W       = (const float*)d_in[3];
  const float* bias    = (const float*)d_in[4];
  const float* start_t = (const float*)d_in[5];
  const float* end_t   = (const float*)d_in[6];
  const float* trans   = (const float*)d_in[7];
  float* out = (float*)d_out;

  float* logits  = (float*)d_ws;                      // 294912 floats
  float* segmat  = logits + (size_t)NROWS * NL;       // 64*8*81 floats
  float* num_den = segmat + (size_t)BB * NSEG * 81;   // 64 floats (num)
  int*   lens    = (int*)(num_den + 128);             // 64 ints
  int*   cnt     = lens + 64;                         // 64 ints (arrival)

  logits_kernel<<<2048, 256, 0, stream>>>(hidden, W, bias, mask, logits, lens,
                                          out, cnt);
  scan_kernel<<<96 + NLOGW, 64, 0, stream>>>(logits, labels, start_t, end_t,
                                             trans, out, num_den, lens,
                                             segmat, cnt);
}